// Round 1
// baseline (6595.512 us; speedup 1.0000x reference)
//
#include <hip/hip_runtime.h>

typedef __attribute__((ext_vector_type(4))) float f32x4;
typedef __attribute__((ext_vector_type(8))) short short8;
typedef unsigned int u32;
typedef unsigned short u16;
typedef __attribute__((ext_vector_type(2))) u32 u32x2;
typedef __attribute__((ext_vector_type(4))) u32 u32x4;

#define DEV __device__ __forceinline__

DEV u16 f2b(float f){
  u32 u = __builtin_bit_cast(u32, f);
  u32 r = u + 0x7fffu + ((u >> 16) & 1u);
  return (u16)(r >> 16);
}
DEV u32 pk2(float a, float b){ return (u32)f2b(a) | ((u32)f2b(b) << 16); }

DEV void gload16(const void* g, void* l){
  __builtin_amdgcn_global_load_lds((const __attribute__((address_space(1))) void*)g,
                                   (__attribute__((address_space(3))) void*)l, 16, 0, 0);
}
DEV u32 lds_addr(void* p){
  return (u32)(unsigned long long)(__attribute__((address_space(3))) char*)p;
}

// ---------------- LayerNorm: rows of 1024, fp32 in, bf16 or f32 out ----------
template<int OUT_F32>
__global__ __launch_bounds__(256) void ln_k(const float* __restrict__ x,
    const float* __restrict__ gam, const float* __restrict__ bet,
    void* __restrict__ out)
{
  const int row = blockIdx.x, tid = threadIdx.x;
  const float4 v = ((const float4*)(x + row*1024))[tid];
  float s = (v.x + v.y) + (v.z + v.w);
  float q = (v.x*v.x + v.y*v.y) + (v.z*v.z + v.w*v.w);
  #pragma unroll
  for (int m = 1; m < 64; m <<= 1){ s += __shfl_xor(s, m); q += __shfl_xor(q, m); }
  __shared__ float ps[4], pq[4];
  if ((tid & 63) == 0){ ps[tid>>6] = s; pq[tid>>6] = q; }
  __syncthreads();
  s = (ps[0]+ps[1]) + (ps[2]+ps[3]);
  q = (pq[0]+pq[1]) + (pq[2]+pq[3]);
  const float mean = s * (1.f/1024.f);
  const float var  = q * (1.f/1024.f) - mean*mean;
  const float rstd = rsqrtf(var + 1e-5f);
  const float4 gg = ((const float4*)gam)[tid];
  const float4 bb = ((const float4*)bet)[tid];
  const float o0 = (v.x-mean)*rstd*gg.x + bb.x;
  const float o1 = (v.y-mean)*rstd*gg.y + bb.y;
  const float o2 = (v.z-mean)*rstd*gg.z + bb.z;
  const float o3 = (v.w-mean)*rstd*gg.w + bb.w;
  if (OUT_F32){
    float4 r; r.x=o0; r.y=o1; r.z=o2; r.w=o3;
    ((float4*)out)[row*256 + tid] = r;
  } else {
    u32x2 r; r.x = pk2(o0,o1); r.y = pk2(o2,o3);
    ((u32x2*)out)[row*256 + tid] = r;
  }
}

// ---------------- GEMM: C[M,N] = A[M,K](bf16) * W[N,K]^T(f32) + bias ---------
// 128x128 tile, BK=64, 4 waves (2x2), mfma 16x16x32 bf16.
// A staged via global_load_lds (swizzled source), W reg-staged + cvt bf16.
template<int DO_GELU, int DO_RES, int OUT_F32>
__global__ __launch_bounds__(256,2) void gemm_k(
    const u16* __restrict__ A, const float* __restrict__ W,
    const float* __restrict__ bias, const float* __restrict__ res,
    void* __restrict__ Cout, int M, int N, int K)
{
  __shared__ char sA[16384];
  __shared__ char sB[16384];
  const int tid = threadIdx.x;
  const int lane = tid & 63, w = tid >> 6;
  const int wr = w >> 1, wc = w & 1;
  const int g = lane >> 4, c16 = lane & 15;
  const int m0 = blockIdx.y * 128, n0 = blockIdx.x * 128;

  f32x4 acc[4][4];
  #pragma unroll
  for (int m = 0; m < 4; m++)
    #pragma unroll
    for (int n = 0; n < 4; n++) acc[m][n] = (f32x4){0.f,0.f,0.f,0.f};

  const int arow = tid >> 3, achk = tid & 7;
  const int acg = achk ^ (arow & 7);          // low 3 bits of row invariant to +32
  const u16*   aSrc = A + (m0 + arow)*K + acg*8;
  const float* wSrc = W + (n0 + arow)*K + achk*8;
  char* aDst = sA + w*1024;
  char* bDst = sB + arow*128 + acg*16;

  for (int kk = 0; kk < K; kk += 64){
    __syncthreads();
    #pragma unroll
    for (int i = 0; i < 4; i++)
      gload16(aSrc + i*32*K + kk, aDst + i*4096);
    #pragma unroll
    for (int it = 0; it < 4; it++){
      const float4 v0 = *(const float4*)(wSrc + it*32*K + kk);
      const float4 v1 = *(const float4*)(wSrc + it*32*K + kk + 4);
      u32x4 pv;
      pv.x = pk2(v0.x, v0.y); pv.y = pk2(v0.z, v0.w);
      pv.z = pk2(v1.x, v1.y); pv.w = pk2(v1.z, v1.w);
      *(u32x4*)(bDst + it*32*128) = pv;
    }
    __syncthreads();
    #pragma unroll
    for (int ks = 0; ks < 2; ks++){
      short8 af[4], bf[4];
      #pragma unroll
      for (int m = 0; m < 4; m++){
        const int row = wr*64 + m*16 + c16;
        af[m] = *(const short8*)(sA + row*128 + (((ks*4 + g) ^ (row & 7)) << 4));
      }
      #pragma unroll
      for (int n = 0; n < 4; n++){
        const int row = wc*64 + n*16 + c16;
        bf[n] = *(const short8*)(sB + row*128 + (((ks*4 + g) ^ (row & 7)) << 4));
      }
      #pragma unroll
      for (int m = 0; m < 4; m++)
        #pragma unroll
        for (int n = 0; n < 4; n++)
          acc[m][n] = __builtin_amdgcn_mfma_f32_16x16x32_bf16(af[m], bf[n], acc[m][n], 0,0,0);
    }
  }
  #pragma unroll
  for (int n = 0; n < 4; n++){
    const int col = n0 + wc*64 + n*16 + c16;
    const float bv = bias[col];
    #pragma unroll
    for (int m = 0; m < 4; m++){
      const int rbase = m0 + wr*64 + m*16 + g*4;
      #pragma unroll
      for (int r = 0; r < 4; r++){
        float v = acc[m][n][r] + bv;
        if (DO_GELU) v = 0.5f*v*(1.f + erff(v*0.70710678118654752f));
        if (DO_RES)  v += res[(rbase + r)*N + col];
        if (OUT_F32) ((float*)Cout)[(rbase + r)*N + col] = v;
        else         ((u16*)Cout)[(rbase + r)*N + col] = f2b(v);
      }
    }
  }
}

// ---------------- Flash attention, HD=64, Sq=Sk=512 --------------------------
// Swapped QK^T: C'[j][q] = mfma(K_tile, Q^T). Lane owns q = lane&15.
// PV: O^T = mfma(V^T (tr-read), P^T (shuffled)). 64 q-rows/block, 32 j/chunk.
template<int CAUSAL>
__global__ __launch_bounds__(256,2) void attn_k(
    const u16* __restrict__ Qb, int qB, int qS,
    const u16* __restrict__ Kb, int kB, int kS,
    const u16* __restrict__ Vb, int vB, int vS,
    u16* __restrict__ Ob, int oB, int oS, float scale)
{
  __shared__ char smem[8192];
  char* Ks = smem;
  char* Vs = smem + 4096;
  const int tid = threadIdx.x;
  const int lane = tid & 63, w = tid >> 6;
  const int g = lane >> 4, c16 = lane & 15;
  const int qt = blockIdx.x, bh = blockIdx.y;
  const int b = bh >> 4, h = bh & 15;
  const u16* Q  = Qb + b*qB + h*64;
  const u16* Kp = Kb + b*kB + h*64;
  const u16* Vp = Vb + b*vB + h*64;
  u16*       Op = Ob + b*oB + h*64;

  const int qrow = qt*64 + w*16 + c16;
  const short8 bq0 = *(const short8*)(Q + qrow*qS + g*8);
  const short8 bq1 = *(const short8*)(Q + qrow*qS + 32 + g*8);

  f32x4 o[4];
  #pragma unroll
  for (int d = 0; d < 4; d++) o[d] = (f32x4){0.f,0.f,0.f,0.f};
  float mrun = -__builtin_inff(), lrun = 0.f;

  const int srow = tid >> 3, schk = tid & 7;
  const u16* kSrc = Kp + srow*kS + (schk ^ (srow & 7))*8;  // swizzled source
  const u16* vSrc = Vp + srow*vS + schk*8;                 // linear
  char* kDst = Ks + w*1024;
  char* vDst = Vs + w*1024;
  // tr-read per-lane base: row = 8g + (c16>>2), byte col = (c16&3)*8
  const u32 vtr = lds_addr(Vs) + (8*g + (c16 >> 2))*128 + (c16 & 3)*8;

  const int nCh = CAUSAL ? (2*qt + 2) : 16;
  for (int jc = 0; jc < nCh; ++jc){
    const int j0 = jc*32;
    gload16(kSrc + j0*kS, kDst);
    gload16(vSrc + j0*vS, vDst);
    __syncthreads();

    f32x4 st[2];
    #pragma unroll
    for (int t = 0; t < 2; t++){
      const int row = t*16 + c16;
      const int rx = row & 7;
      const short8 ka0 = *(const short8*)(Ks + row*128 + ((g ^ rx) << 4));
      const short8 ka1 = *(const short8*)(Ks + row*128 + (((4 + g) ^ rx) << 4));
      f32x4 z = (f32x4){0.f,0.f,0.f,0.f};
      z = __builtin_amdgcn_mfma_f32_16x16x32_bf16(ka0, bq0, z, 0,0,0);
      z = __builtin_amdgcn_mfma_f32_16x16x32_bf16(ka1, bq1, z, 0,0,0);
      st[t] = z;
    }
    float mloc = -__builtin_inff();
    #pragma unroll
    for (int t = 0; t < 2; t++)
      #pragma unroll
      for (int r = 0; r < 4; r++){
        float sv = st[t][r]*scale;
        if (CAUSAL){ if (j0 + t*16 + g*4 + r > qrow) sv = -__builtin_inff(); }
        st[t][r] = sv;
        mloc = fmaxf(mloc, sv);
      }
    mloc = fmaxf(mloc, __shfl_xor(mloc, 16));
    mloc = fmaxf(mloc, __shfl_xor(mloc, 32));
    const float mnew = fmaxf(mrun, mloc);
    const float corr = __expf(mrun - mnew);
    float psum = 0.f;
    u32 pk00, pk01, pk10, pk11;
    {
      float p0 = __expf(st[0][0]-mnew), p1 = __expf(st[0][1]-mnew);
      float p2 = __expf(st[0][2]-mnew), p3 = __expf(st[0][3]-mnew);
      psum += (p0+p1) + (p2+p3);
      pk00 = pk2(p0,p1); pk01 = pk2(p2,p3);
      p0 = __expf(st[1][0]-mnew); p1 = __expf(st[1][1]-mnew);
      p2 = __expf(st[1][2]-mnew); p3 = __expf(st[1][3]-mnew);
      psum += (p0+p1) + (p2+p3);
      pk10 = pk2(p0,p1); pk11 = pk2(p2,p3);
    }
    psum += __shfl_xor(psum, 16);
    psum += __shfl_xor(psum, 32);
    lrun = lrun*corr + psum;
    mrun = mnew;
    #pragma unroll
    for (int d = 0; d < 4; d++){
      o[d][0]*=corr; o[d][1]*=corr; o[d][2]*=corr; o[d][3]*=corr;
    }
    // redistribute P: dest lane (g,c) reg u <- lane (c | ((2g+(u>>1))&3)<<4),
    // tile (g>>1), pair (u&1)
    const int sl0 = c16 | (((g << 1)     & 3) << 4);
    const int sl1 = c16 | ((((g << 1)+1) & 3) << 4);
    const u32 a00 = (u32)__shfl((int)pk00, sl0), a01 = (u32)__shfl((int)pk01, sl0);
    const u32 a02 = (u32)__shfl((int)pk00, sl1), a03 = (u32)__shfl((int)pk01, sl1);
    const u32 a10 = (u32)__shfl((int)pk10, sl0), a11 = (u32)__shfl((int)pk11, sl0);
    const u32 a12 = (u32)__shfl((int)pk10, sl1), a13 = (u32)__shfl((int)pk11, sl1);
    const bool hi = g >= 2;
    union { short8 s; u32 u[4]; } pb;
    pb.u[0] = hi ? a10 : a00;
    pb.u[1] = hi ? a11 : a01;
    pb.u[2] = hi ? a12 : a02;
    pb.u[3] = hi ? a13 : a03;

    u32x2 t00,t01,t10,t11,t20,t21,t30,t31;
    asm volatile("ds_read_b64_tr_b16 %0, %1 offset:0"   : "=v"(t00) : "v"(vtr));
    asm volatile("ds_read_b64_tr_b16 %0, %1 offset:512" : "=v"(t01) : "v"(vtr));
    asm volatile("ds_read_b64_tr_b16 %0, %1 offset:32"  : "=v"(t10) : "v"(vtr));
    asm volatile("ds_read_b64_tr_b16 %0, %1 offset:544" : "=v"(t11) : "v"(vtr));
    asm volatile("ds_read_b64_tr_b16 %0, %1 offset:64"  : "=v"(t20) : "v"(vtr));
    asm volatile("ds_read_b64_tr_b16 %0, %1 offset:576" : "=v"(t21) : "v"(vtr));
    asm volatile("ds_read_b64_tr_b16 %0, %1 offset:96"  : "=v"(t30) : "v"(vtr));
    asm volatile("ds_read_b64_tr_b16 %0, %1 offset:608" : "=v"(t31) : "v"(vtr));
    asm volatile("s_waitcnt lgkmcnt(0)" ::: "memory");
    __builtin_amdgcn_sched_barrier(0);
    union { short8 s; u32x2 d[2]; } v0u, v1u, v2u, v3u;
    v0u.d[0]=t00; v0u.d[1]=t01;
    v1u.d[0]=t10; v1u.d[1]=t11;
    v2u.d[0]=t20; v2u.d[1]=t21;
    v3u.d[0]=t30; v3u.d[1]=t31;
    o[0] = __builtin_amdgcn_mfma_f32_16x16x32_bf16(v0u.s, pb.s, o[0], 0,0,0);
    o[1] = __builtin_amdgcn_mfma_f32_16x16x32_bf16(v1u.s, pb.s, o[1], 0,0,0);
    o[2] = __builtin_amdgcn_mfma_f32_16x16x32_bf16(v2u.s, pb.s, o[2], 0,0,0);
    o[3] = __builtin_amdgcn_mfma_f32_16x16x32_bf16(v3u.s, pb.s, o[3], 0,0,0);
    __syncthreads();
  }
  // epilogue: O^T frags -> LDS [64 q][64 d] bf16 (swizzled) -> coalesced store
  const float inv = 1.f / lrun;
  char* Olds = smem;
  #pragma unroll
  for (int dd = 0; dd < 4; dd++){
    u32x2 val;
    val.x = pk2(o[dd][0]*inv, o[dd][1]*inv);
    val.y = pk2(o[dd][2]*inv, o[dd][3]*inv);
    const int row = w*16 + c16;
    const int off = 32*dd + 8*g;
    const int chunk = off >> 4, rem = off & 15;
    *(u32x2*)(Olds + row*128 + ((chunk ^ (row & 7)) << 4) + rem) = val;
  }
  __syncthreads();
  const int orow = tid >> 2, oc = tid & 3;
  #pragma unroll
  for (int i = 0; i < 2; i++){
    const int ch = oc*2 + i;
    const u32x4 vv = *(const u32x4*)(Olds + orow*128 + ((ch ^ (orow & 7)) << 4));
    *(u32x4*)(Op + (qt*64 + orow)*oS + ch*8) = vv;
  }
}

// ----------------------------------------------------------------------------
extern "C" void kernel_launch(void* const* d_in, const int* in_sizes, int n_in,
                              void* d_out, int out_size, void* d_ws, size_t ws_size,
                              hipStream_t stream)
{
  (void)in_sizes; (void)n_in; (void)out_size; (void)ws_size;
  const float* src      = (const float*)d_in[0];
  const float* tgt      = (const float*)d_in[1];
  const float* e_qkv_w  = (const float*)d_in[2];
  const float* e_qkv_b  = (const float*)d_in[3];
  const float* e_out_w  = (const float*)d_in[4];
  const float* e_out_b  = (const float*)d_in[5];
  const float* e_ln1_g  = (const float*)d_in[6];
  const float* e_ln1_b  = (const float*)d_in[7];
  const float* e_fc1_w  = (const float*)d_in[8];
  const float* e_fc1_b  = (const float*)d_in[9];
  const float* e_fc2_w  = (const float*)d_in[10];
  const float* e_fc2_b  = (const float*)d_in[11];
  const float* e_ln2_g  = (const float*)d_in[12];
  const float* e_ln2_b  = (const float*)d_in[13];
  const float* e_nrm_g  = (const float*)d_in[14];
  const float* e_nrm_b  = (const float*)d_in[15];
  const float* dc_qkv_w = (const float*)d_in[16];
  const float* dc_qkv_b = (const float*)d_in[17];
  const float* dc_sout_w= (const float*)d_in[18];
  const float* dc_sout_b= (const float*)d_in[19];
  const float* dc_ln1_g = (const float*)d_in[20];
  const float* dc_ln1_b = (const float*)d_in[21];
  const float* dc_q_w   = (const float*)d_in[22];
  const float* dc_q_b   = (const float*)d_in[23];
  const float* dc_kv_w  = (const float*)d_in[24];
  const float* dc_kv_b  = (const float*)d_in[25];
  const float* dc_cout_w= (const float*)d_in[26];
  const float* dc_cout_b= (const float*)d_in[27];
  const float* dc_ln2_g = (const float*)d_in[28];
  const float* dc_ln2_b = (const float*)d_in[29];
  const float* dc_fc1_w = (const float*)d_in[30];
  const float* dc_fc1_b = (const float*)d_in[31];
  const float* dc_fc2_w = (const float*)d_in[32];
  const float* dc_fc2_b = (const float*)d_in[33];
  const float* dc_ln3_g = (const float*)d_in[34];
  const float* dc_ln3_b = (const float*)d_in[35];
  const float* dc_nrm_g = (const float*)d_in[36];
  const float* dc_nrm_b = (const float*)d_in[37];

  char* ws = (char*)d_ws;
  u16*  ln_out = (u16*)(ws);                    //  8 MB
  u16*  attn_o = (u16*)(ws + (8u<<20));         //  8 MB
  u16*  membuf = (u16*)(ws + (16u<<20));        //  8 MB
  float* xres  = (float*)(ws + (24u<<20));      // 16 MB
  u16*  region = (u16*)(ws + (40u<<20));        // 32 MB (qkv | hbuf | qbuf+kvbuf)
  u16*  qkv   = region;
  u16*  hbuf  = region;
  u16*  qbuf  = region;
  u16*  kvbuf = region + (4u<<20);              // +8MB in elements

  const dim3 blk(256);
  const int M = 4096;

  // ----------------- encoder -----------------
  for (int i = 0; i < 6; i++){
    const float* xin = i ? xres : src;
    ln_k<0><<<4096, blk, 0, stream>>>(xin, e_ln1_g + i*1024, e_ln1_b + i*1024, ln_out);
    gemm_k<0,0,0><<<dim3(3072/128, 32), blk, 0, stream>>>(ln_out,
        e_qkv_w + (size_t)i*3145728, e_qkv_b + i*3072, nullptr, qkv, M, 3072, 1024);
    attn_k<0><<<dim3(8,128), blk, 0, stream>>>(qkv, 3072, 24576,
        qkv+1024, 3072, 24576, qkv+2048, 3072, 24576, attn_o, 1024, 8192, 0.125f);
    gemm_k<0,1,1><<<dim3(1024/128, 32), blk, 0, stream>>>(attn_o,
        e_out_w + (size_t)i*1048576, e_out_b + i*1024, xin, xres, M, 1024, 1024);
    ln_k<0><<<4096, blk, 0, stream>>>(xres, e_ln2_g + i*1024, e_ln2_b + i*1024, ln_out);
    gemm_k<1,0,0><<<dim3(4096/128, 32), blk, 0, stream>>>(ln_out,
        e_fc1_w + (size_t)i*4194304, e_fc1_b + i*4096, nullptr, hbuf, M, 4096, 1024);
    gemm_k<0,1,1><<<dim3(1024/128, 32), blk, 0, stream>>>(hbuf,
        e_fc2_w + (size_t)i*4194304, e_fc2_b + i*1024, xres, xres, M, 1024, 4096);
  }
  ln_k<0><<<4096, blk, 0, stream>>>(xres, e_nrm_g, e_nrm_b, membuf);

  // ----------------- decoder -----------------
  for (int i = 0; i < 6; i++){
    const float* yin = i ? xres : tgt;
    ln_k<0><<<4096, blk, 0, stream>>>(yin, dc_ln1_g + i*1024, dc_ln1_b + i*1024, ln_out);
    gemm_k<0,0,0><<<dim3(3072/128, 32), blk, 0, stream>>>(ln_out,
        dc_qkv_w + (size_t)i*3145728, dc_qkv_b + i*3072, nullptr, qkv, M, 3072, 1024);
    attn_k<1><<<dim3(8,128), blk, 0, stream>>>(qkv, 3072, 24576,
        qkv+1024, 3072, 24576, qkv+2048, 3072, 24576, attn_o, 1024, 8192, 0.125f);
    gemm_k<0,1,1><<<dim3(1024/128, 32), blk, 0, stream>>>(attn_o,
        dc_sout_w + (size_t)i*1048576, dc_sout_b + i*1024, yin, xres, M, 1024, 1024);
    ln_k<0><<<4096, blk, 0, stream>>>(xres, dc_ln2_g + i*1024, dc_ln2_b + i*1024, ln_out);
    gemm_k<0,0,0><<<dim3(1024/128, 32), blk, 0, stream>>>(ln_out,
        dc_q_w + (size_t)i*1048576, dc_q_b + i*1024, nullptr, qbuf, M, 1024, 1024);
    gemm_k<0,0,0><<<dim3(2048/128, 32), blk, 0, stream>>>(membuf,
        dc_kv_w + (size_t)i*2097152, dc_kv_b + i*2048, nullptr, kvbuf, M, 2048, 1024);
    attn_k<0><<<dim3(8,128), blk, 0, stream>>>(qbuf, 1024, 8192,
        kvbuf, 2048, 16384, kvbuf+1024, 2048, 16384, attn_o, 1024, 8192, 0.125f);
    gemm_k<0,1,1><<<dim3(1024/128, 32), blk, 0, stream>>>(attn_o,
        dc_cout_w + (size_t)i*1048576, dc_cout_b + i*1024, xres, xres, M, 1024, 1024);
    ln_k<0><<<4096, blk, 0, stream>>>(xres, dc_ln3_g + i*1024, dc_ln3_b + i*1024, ln_out);
    gemm_k<1,0,0><<<dim3(4096/128, 32), blk, 0, stream>>>(ln_out,
        dc_fc1_w + (size_t)i*4194304, dc_fc1_b + i*4096, nullptr, hbuf, M, 4096, 1024);
    gemm_k<0,1,1><<<dim3(1024/128, 32), blk, 0, stream>>>(hbuf,
        dc_fc2_w + (size_t)i*4194304, dc_fc2_b + i*1024, xres, xres, M, 1024, 4096);
  }
  ln_k<1><<<4096, blk, 0, stream>>>(xres, dc_nrm_g, dc_nrm_b, d_out);
}

// Round 2
// 3922.419 us; speedup vs baseline: 1.6815x; 1.6815x over previous
//
#include <hip/hip_runtime.h>

typedef __attribute__((ext_vector_type(4))) float f32x4;
typedef __attribute__((ext_vector_type(8))) short short8;
typedef unsigned int u32;
typedef unsigned short u16;
typedef __attribute__((ext_vector_type(2))) u32 u32x2;
typedef __attribute__((ext_vector_type(4))) u32 u32x4;

#define DEV __device__ __forceinline__

DEV u16 f2b(float f){
  u32 u = __builtin_bit_cast(u32, f);
  u32 r = u + 0x7fffu + ((u >> 16) & 1u);
  return (u16)(r >> 16);
}
DEV u32 pk2(float a, float b){ return (u32)f2b(a) | ((u32)f2b(b) << 16); }

DEV void gload16(const void* g, void* l){
  __builtin_amdgcn_global_load_lds((const __attribute__((address_space(1))) void*)g,
                                   (__attribute__((address_space(3))) void*)l, 16, 0, 0);
}
DEV u32 lds_addr(void* p){
  return (u32)(unsigned long long)(__attribute__((address_space(3))) char*)p;
}

// ---------------- fp32 -> bf16 conversion (memory-bound, 8 elems/thread/iter)
__global__ __launch_bounds__(256) void cvt_k(const float* __restrict__ in,
                                             u16* __restrict__ out, int n8)
{
  int i = blockIdx.x*256 + threadIdx.x;
  const int stride = gridDim.x*256;
  for (; i < n8; i += stride){
    const float4 a = ((const float4*)in)[2*i];
    const float4 b = ((const float4*)in)[2*i+1];
    u32x4 r;
    r.x = pk2(a.x,a.y); r.y = pk2(a.z,a.w);
    r.z = pk2(b.x,b.y); r.w = pk2(b.z,b.w);
    ((u32x4*)out)[i] = r;
  }
}

// ---------------- LayerNorm: rows of 1024, fp32 in, bf16 or f32 out ----------
template<int OUT_F32>
__global__ __launch_bounds__(256) void ln_k(const float* __restrict__ x,
    const float* __restrict__ gam, const float* __restrict__ bet,
    void* __restrict__ out)
{
  const int row = blockIdx.x, tid = threadIdx.x;
  const float4 v = ((const float4*)(x + row*1024))[tid];
  float s = (v.x + v.y) + (v.z + v.w);
  float q = (v.x*v.x + v.y*v.y) + (v.z*v.z + v.w*v.w);
  #pragma unroll
  for (int m = 1; m < 64; m <<= 1){ s += __shfl_xor(s, m); q += __shfl_xor(q, m); }
  __shared__ float ps[4], pq[4];
  if ((tid & 63) == 0){ ps[tid>>6] = s; pq[tid>>6] = q; }
  __syncthreads();
  s = (ps[0]+ps[1]) + (ps[2]+ps[3]);
  q = (pq[0]+pq[1]) + (pq[2]+pq[3]);
  const float mean = s * (1.f/1024.f);
  const float var  = q * (1.f/1024.f) - mean*mean;
  const float rstd = rsqrtf(var + 1e-5f);
  const float4 gg = ((const float4*)gam)[tid];
  const float4 bb = ((const float4*)bet)[tid];
  const float o0 = (v.x-mean)*rstd*gg.x + bb.x;
  const float o1 = (v.y-mean)*rstd*gg.y + bb.y;
  const float o2 = (v.z-mean)*rstd*gg.z + bb.z;
  const float o3 = (v.w-mean)*rstd*gg.w + bb.w;
  if (OUT_F32){
    float4 r; r.x=o0; r.y=o1; r.z=o2; r.w=o3;
    ((float4*)out)[row*256 + tid] = r;
  } else {
    u32x2 r; r.x = pk2(o0,o1); r.y = pk2(o2,o3);
    ((u32x2*)out)[row*256 + tid] = r;
  }
}

// ---------------- GEMM: C[M,N] = A[M,K](bf16) * W[N,K]^T(bf16) + bias --------
// 128x128 tile, BK=64, 4 waves (2x2), mfma 16x16x32 bf16. Both operands staged
// via global_load_lds width=16 with pre-swizzled global source (m97 structure).
// Grid: x = M-blocks (fast), y = N-blocks; bijective XCD chunk swizzle (m204)
// so consecutive blocks on one XCD share the same W panel in its L2.
template<int DO_GELU, int DO_RES, int OUT_F32>
__global__ __launch_bounds__(256,2) void gemm_k(
    const u16* __restrict__ A, const u16* __restrict__ W,
    const float* __restrict__ bias, const float* __restrict__ res,
    void* __restrict__ Cout, int M, int N, int K)
{
  __shared__ char sA[16384];
  __shared__ char sB[16384];
  const int tid = threadIdx.x;
  const int lane = tid & 63, w = tid >> 6;
  const int wr = w >> 1, wc = w & 1;
  const int g = lane >> 4, c16 = lane & 15;

  // XCD-aware bijective remap of flattened block id
  const u32 nwg = gridDim.x * gridDim.y;
  u32 flat = blockIdx.x + gridDim.x * blockIdx.y;
  {
    const u32 q = nwg >> 3, r = nwg & 7;
    const u32 xcd = flat & 7, idx = flat >> 3;
    flat = (xcd < r ? xcd*(q+1) : r*(q+1) + (xcd-r)*q) + idx;
  }
  const int m0 = (int)(flat % gridDim.x) * 128;
  const int n0 = (int)(flat / gridDim.x) * 128;

  f32x4 acc[4][4];
  #pragma unroll
  for (int m = 0; m < 4; m++)
    #pragma unroll
    for (int n = 0; n < 4; n++) acc[m][n] = (f32x4){0.f,0.f,0.f,0.f};

  const int arow = tid >> 3, achk = tid & 7;
  const int acg = achk ^ (arow & 7);          // pre-swizzled source chunk
  const u16* aSrc = A + (size_t)(m0 + arow)*K + acg*8;
  const u16* wSrc = W + (size_t)(n0 + arow)*K + acg*8;
  char* aDst = sA + w*1024;
  char* bDst = sB + w*1024;

  for (int kk = 0; kk < K; kk += 64){
    __syncthreads();
    #pragma unroll
    for (int i = 0; i < 4; i++){
      gload16(aSrc + i*32*K + kk, aDst + i*4096);
      gload16(wSrc + i*32*K + kk, bDst + i*4096);
    }
    __syncthreads();
    #pragma unroll
    for (int ks = 0; ks < 2; ks++){
      short8 af[4], bf[4];
      #pragma unroll
      for (int m = 0; m < 4; m++){
        const int row = wr*64 + m*16 + c16;
        af[m] = *(const short8*)(sA + row*128 + (((ks*4 + g) ^ (row & 7)) << 4));
      }
      #pragma unroll
      for (int n = 0; n < 4; n++){
        const int row = wc*64 + n*16 + c16;
        bf[n] = *(const short8*)(sB + row*128 + (((ks*4 + g) ^ (row & 7)) << 4));
      }
      #pragma unroll
      for (int m = 0; m < 4; m++)
        #pragma unroll
        for (int n = 0; n < 4; n++)
          acc[m][n] = __builtin_amdgcn_mfma_f32_16x16x32_bf16(af[m], bf[n], acc[m][n], 0,0,0);
    }
  }
  #pragma unroll
  for (int n = 0; n < 4; n++){
    const int col = n0 + wc*64 + n*16 + c16;
    const float bv = bias[col];
    #pragma unroll
    for (int m = 0; m < 4; m++){
      const int rbase = m0 + wr*64 + m*16 + g*4;
      #pragma unroll
      for (int r = 0; r < 4; r++){
        float v = acc[m][n][r] + bv;
        if (DO_GELU) v = 0.5f*v*(1.f + erff(v*0.70710678118654752f));
        if (DO_RES)  v += res[(size_t)(rbase + r)*N + col];
        if (OUT_F32) ((float*)Cout)[(size_t)(rbase + r)*N + col] = v;
        else         ((u16*)Cout)[(size_t)(rbase + r)*N + col] = f2b(v);
      }
    }
  }
}

// ---------------- Flash attention, HD=64, Sq=Sk=512 --------------------------
// Swapped QK^T: C'[j][q] = mfma(K_tile, Q^T). Lane owns q = lane&15.
// PV: O^T = mfma(V^T (tr-read), P^T (shuffled)). 64 q-rows/block, 32 j/chunk.
template<int CAUSAL>
__global__ __launch_bounds__(256,2) void attn_k(
    const u16* __restrict__ Qb, int qB, int qS,
    const u16* __restrict__ Kb, int kB, int kS,
    const u16* __restrict__ Vb, int vB, int vS,
    u16* __restrict__ Ob, int oB, int oS, float scale)
{
  __shared__ char smem[8192];
  char* Ks = smem;
  char* Vs = smem + 4096;
  const int tid = threadIdx.x;
  const int lane = tid & 63, w = tid >> 6;
  const int g = lane >> 4, c16 = lane & 15;
  const int qt = blockIdx.x, bh = blockIdx.y;
  const int b = bh >> 4, h = bh & 15;
  const u16* Q  = Qb + b*qB + h*64;
  const u16* Kp = Kb + b*kB + h*64;
  const u16* Vp = Vb + b*vB + h*64;
  u16*       Op = Ob + b*oB + h*64;

  const int qrow = qt*64 + w*16 + c16;
  const short8 bq0 = *(const short8*)(Q + qrow*qS + g*8);
  const short8 bq1 = *(const short8*)(Q + qrow*qS + 32 + g*8);

  f32x4 o[4];
  #pragma unroll
  for (int d = 0; d < 4; d++) o[d] = (f32x4){0.f,0.f,0.f,0.f};
  float mrun = -__builtin_inff(), lrun = 0.f;

  const int srow = tid >> 3, schk = tid & 7;
  const u16* kSrc = Kp + srow*kS + (schk ^ (srow & 7))*8;  // swizzled source
  const u16* vSrc = Vp + srow*vS + schk*8;                 // linear
  char* kDst = Ks + w*1024;
  char* vDst = Vs + w*1024;
  // tr-read per-lane base: row = 8g + (c16>>2), byte col = (c16&3)*8
  const u32 vtr = lds_addr(Vs) + (8*g + (c16 >> 2))*128 + (c16 & 3)*8;

  const int nCh = CAUSAL ? (2*qt + 2) : 16;
  for (int jc = 0; jc < nCh; ++jc){
    const int j0 = jc*32;
    gload16(kSrc + j0*kS, kDst);
    gload16(vSrc + j0*vS, vDst);
    __syncthreads();

    f32x4 st[2];
    #pragma unroll
    for (int t = 0; t < 2; t++){
      const int row = t*16 + c16;
      const int rx = row & 7;
      const short8 ka0 = *(const short8*)(Ks + row*128 + ((g ^ rx) << 4));
      const short8 ka1 = *(const short8*)(Ks + row*128 + (((4 + g) ^ rx) << 4));
      f32x4 z = (f32x4){0.f,0.f,0.f,0.f};
      z = __builtin_amdgcn_mfma_f32_16x16x32_bf16(ka0, bq0, z, 0,0,0);
      z = __builtin_amdgcn_mfma_f32_16x16x32_bf16(ka1, bq1, z, 0,0,0);
      st[t] = z;
    }
    float mloc = -__builtin_inff();
    #pragma unroll
    for (int t = 0; t < 2; t++)
      #pragma unroll
      for (int r = 0; r < 4; r++){
        float sv = st[t][r]*scale;
        if (CAUSAL){ if (j0 + t*16 + g*4 + r > qrow) sv = -__builtin_inff(); }
        st[t][r] = sv;
        mloc = fmaxf(mloc, sv);
      }
    mloc = fmaxf(mloc, __shfl_xor(mloc, 16));
    mloc = fmaxf(mloc, __shfl_xor(mloc, 32));
    const float mnew = fmaxf(mrun, mloc);
    const float corr = __expf(mrun - mnew);
    float psum = 0.f;
    u32 pk00, pk01, pk10, pk11;
    {
      float p0 = __expf(st[0][0]-mnew), p1 = __expf(st[0][1]-mnew);
      float p2 = __expf(st[0][2]-mnew), p3 = __expf(st[0][3]-mnew);
      psum += (p0+p1) + (p2+p3);
      pk00 = pk2(p0,p1); pk01 = pk2(p2,p3);
      p0 = __expf(st[1][0]-mnew); p1 = __expf(st[1][1]-mnew);
      p2 = __expf(st[1][2]-mnew); p3 = __expf(st[1][3]-mnew);
      psum += (p0+p1) + (p2+p3);
      pk10 = pk2(p0,p1); pk11 = pk2(p2,p3);
    }
    psum += __shfl_xor(psum, 16);
    psum += __shfl_xor(psum, 32);
    lrun = lrun*corr + psum;
    mrun = mnew;
    #pragma unroll
    for (int d = 0; d < 4; d++){
      o[d][0]*=corr; o[d][1]*=corr; o[d][2]*=corr; o[d][3]*=corr;
    }
    // redistribute P: dest lane (g,c) reg u <- lane (c | ((2g+(u>>1))&3)<<4)
    const int sl0 = c16 | (((g << 1)     & 3) << 4);
    const int sl1 = c16 | ((((g << 1)+1) & 3) << 4);
    const u32 a00 = (u32)__shfl((int)pk00, sl0), a01 = (u32)__shfl((int)pk01, sl0);
    const u32 a02 = (u32)__shfl((int)pk00, sl1), a03 = (u32)__shfl((int)pk01, sl1);
    const u32 a10 = (u32)__shfl((int)pk10, sl0), a11 = (u32)__shfl((int)pk11, sl0);
    const u32 a12 = (u32)__shfl((int)pk10, sl1), a13 = (u32)__shfl((int)pk11, sl1);
    const bool hi = g >= 2;
    union { short8 s; u32 u[4]; } pb;
    pb.u[0] = hi ? a10 : a00;
    pb.u[1] = hi ? a11 : a01;
    pb.u[2] = hi ? a12 : a02;
    pb.u[3] = hi ? a13 : a03;

    u32x2 t00,t01,t10,t11,t20,t21,t30,t31;
    asm volatile("ds_read_b64_tr_b16 %0, %1 offset:0"   : "=v"(t00) : "v"(vtr));
    asm volatile("ds_read_b64_tr_b16 %0, %1 offset:512" : "=v"(t01) : "v"(vtr));
    asm volatile("ds_read_b64_tr_b16 %0, %1 offset:32"  : "=v"(t10) : "v"(vtr));
    asm volatile("ds_read_b64_tr_b16 %0, %1 offset:544" : "=v"(t11) : "v"(vtr));
    asm volatile("ds_read_b64_tr_b16 %0, %1 offset:64"  : "=v"(t20) : "v"(vtr));
    asm volatile("ds_read_b64_tr_b16 %0, %1 offset:576" : "=v"(t21) : "v"(vtr));
    asm volatile("ds_read_b64_tr_b16 %0, %1 offset:96"  : "=v"(t30) : "v"(vtr));
    asm volatile("ds_read_b64_tr_b16 %0, %1 offset:608" : "=v"(t31) : "v"(vtr));
    asm volatile("s_waitcnt lgkmcnt(0)" ::: "memory");
    __builtin_amdgcn_sched_barrier(0);
    union { short8 s; u32x2 d[2]; } v0u, v1u, v2u, v3u;
    v0u.d[0]=t00; v0u.d[1]=t01;
    v1u.d[0]=t10; v1u.d[1]=t11;
    v2u.d[0]=t20; v2u.d[1]=t21;
    v3u.d[0]=t30; v3u.d[1]=t31;
    o[0] = __builtin_amdgcn_mfma_f32_16x16x32_bf16(v0u.s, pb.s, o[0], 0,0,0);
    o[1] = __builtin_amdgcn_mfma_f32_16x16x32_bf16(v1u.s, pb.s, o[1], 0,0,0);
    o[2] = __builtin_amdgcn_mfma_f32_16x16x32_bf16(v2u.s, pb.s, o[2], 0,0,0);
    o[3] = __builtin_amdgcn_mfma_f32_16x16x32_bf16(v3u.s, pb.s, o[3], 0,0,0);
    __syncthreads();
  }
  // epilogue: O^T frags -> LDS [64 q][64 d] bf16 (swizzled) -> coalesced store
  const float inv = 1.f / lrun;
  char* Olds = smem;
  #pragma unroll
  for (int dd = 0; dd < 4; dd++){
    u32x2 val;
    val.x = pk2(o[dd][0]*inv, o[dd][1]*inv);
    val.y = pk2(o[dd][2]*inv, o[dd][3]*inv);
    const int row = w*16 + c16;
    const int off = 32*dd + 8*g;
    const int chunk = off >> 4, rem = off & 15;
    *(u32x2*)(Olds + row*128 + ((chunk ^ (row & 7)) << 4) + rem) = val;
  }
  __syncthreads();
  const int orow = tid >> 2, oc = tid & 3;
  #pragma unroll
  for (int i = 0; i < 2; i++){
    const int ch = oc*2 + i;
    const u32x4 vv = *(const u32x4*)(Olds + orow*128 + ((ch ^ (orow & 7)) << 4));
    *(u32x4*)(Op + (qt*64 + orow)*oS + ch*8) = vv;
  }
}

// ----------------------------------------------------------------------------
static inline int cvt_grid(int n8){ int g = (n8 + 255) / 256; return g > 2048 ? 2048 : g; }

extern "C" void kernel_launch(void* const* d_in, const int* in_sizes, int n_in,
                              void* d_out, int out_size, void* d_ws, size_t ws_size,
                              hipStream_t stream)
{
  (void)in_sizes; (void)n_in; (void)out_size; (void)ws_size;
  const float* src      = (const float*)d_in[0];
  const float* tgt      = (const float*)d_in[1];
  const float* e_qkv_w  = (const float*)d_in[2];
  const float* e_qkv_b  = (const float*)d_in[3];
  const float* e_out_w  = (const float*)d_in[4];
  const float* e_out_b  = (const float*)d_in[5];
  const float* e_ln1_g  = (const float*)d_in[6];
  const float* e_ln1_b  = (const float*)d_in[7];
  const float* e_fc1_w  = (const float*)d_in[8];
  const float* e_fc1_b  = (const float*)d_in[9];
  const float* e_fc2_w  = (const float*)d_in[10];
  const float* e_fc2_b  = (const float*)d_in[11];
  const float* e_ln2_g  = (const float*)d_in[12];
  const float* e_ln2_b  = (const float*)d_in[13];
  const float* e_nrm_g  = (const float*)d_in[14];
  const float* e_nrm_b  = (const float*)d_in[15];
  const float* dc_qkv_w = (const float*)d_in[16];
  const float* dc_qkv_b = (const float*)d_in[17];
  const float* dc_sout_w= (const float*)d_in[18];
  const float* dc_sout_b= (const float*)d_in[19];
  const float* dc_ln1_g = (const float*)d_in[20];
  const float* dc_ln1_b = (const float*)d_in[21];
  const float* dc_q_w   = (const float*)d_in[22];
  const float* dc_q_b   = (const float*)d_in[23];
  const float* dc_kv_w  = (const float*)d_in[24];
  const float* dc_kv_b  = (const float*)d_in[25];
  const float* dc_cout_w= (const float*)d_in[26];
  const float* dc_cout_b= (const float*)d_in[27];
  const float* dc_ln2_g = (const float*)d_in[28];
  const float* dc_ln2_b = (const float*)d_in[29];
  const float* dc_fc1_w = (const float*)d_in[30];
  const float* dc_fc1_b = (const float*)d_in[31];
  const float* dc_fc2_w = (const float*)d_in[32];
  const float* dc_fc2_b = (const float*)d_in[33];
  const float* dc_ln3_g = (const float*)d_in[34];
  const float* dc_ln3_b = (const float*)d_in[35];
  const float* dc_nrm_g = (const float*)d_in[36];
  const float* dc_nrm_b = (const float*)d_in[37];

  char* ws = (char*)d_ws;
  u16*  ln_out = (u16*)(ws);                    //  8 MB
  u16*  attn_o = (u16*)(ws + (8u<<20));         //  8 MB
  u16*  membuf = (u16*)(ws + (16u<<20));        //  8 MB
  float* xres  = (float*)(ws + (24u<<20));      // 16 MB
  u16*  region = (u16*)(ws + (40u<<20));        // 32 MB (qkv | hbuf | qbuf+kvbuf)
  u16*  qkv   = region;
  u16*  hbuf  = region;
  u16*  qbuf  = region;
  u16*  kvbuf = region + (4u<<20);              // +8MB in elements
  u16*  wbuf  = (u16*)(ws + (72u<<20));         // 16 MB (bf16 weight staging)

  const dim3 blk(256);
  const int M = 4096;

  // ----------------- encoder -----------------
  for (int i = 0; i < 6; i++){
    const float* xin = i ? xres : src;
    ln_k<0><<<4096, blk, 0, stream>>>(xin, e_ln1_g + i*1024, e_ln1_b + i*1024, ln_out);
    cvt_k<<<cvt_grid(393216), blk, 0, stream>>>(e_qkv_w + (size_t)i*3145728, wbuf, 393216);
    gemm_k<0,0,0><<<dim3(32, 24), blk, 0, stream>>>(ln_out,
        wbuf, e_qkv_b + i*3072, nullptr, qkv, M, 3072, 1024);
    attn_k<0><<<dim3(8,128), blk, 0, stream>>>(qkv, 3072, 24576,
        qkv+1024, 3072, 24576, qkv+2048, 3072, 24576, attn_o, 1024, 8192, 0.125f);
    cvt_k<<<cvt_grid(131072), blk, 0, stream>>>(e_out_w + (size_t)i*1048576, wbuf, 131072);
    gemm_k<0,1,1><<<dim3(32, 8), blk, 0, stream>>>(attn_o,
        wbuf, e_out_b + i*1024, xin, xres, M, 1024, 1024);
    ln_k<0><<<4096, blk, 0, stream>>>(xres, e_ln2_g + i*1024, e_ln2_b + i*1024, ln_out);
    cvt_k<<<cvt_grid(524288), blk, 0, stream>>>(e_fc1_w + (size_t)i*4194304, wbuf, 524288);
    gemm_k<1,0,0><<<dim3(32, 32), blk, 0, stream>>>(ln_out,
        wbuf, e_fc1_b + i*4096, nullptr, hbuf, M, 4096, 1024);
    cvt_k<<<cvt_grid(524288), blk, 0, stream>>>(e_fc2_w + (size_t)i*4194304, wbuf, 524288);
    gemm_k<0,1,1><<<dim3(32, 8), blk, 0, stream>>>(hbuf,
        wbuf, e_fc2_b + i*1024, xres, xres, M, 1024, 4096);
  }
  ln_k<0><<<4096, blk, 0, stream>>>(xres, e_nrm_g, e_nrm_b, membuf);

  // ----------------- decoder -----------------
  for (int i = 0; i < 6; i++){
    const float* yin = i ? xres : tgt;
    ln_k<0><<<4096, blk, 0, stream>>>(yin, dc_ln1_g + i*1024, dc_ln1_b + i*1024, ln_out);
    cvt_k<<<cvt_grid(393216), blk, 0, stream>>>(dc_qkv_w + (size_t)i*3145728, wbuf, 393216);
    gemm_k<0,0,0><<<dim3(32, 24), blk, 0, stream>>>(ln_out,
        wbuf, dc_qkv_b + i*3072, nullptr, qkv, M, 3072, 1024);
    attn_k<1><<<dim3(8,128), blk, 0, stream>>>(qkv, 3072, 24576,
        qkv+1024, 3072, 24576, qkv+2048, 3072, 24576, attn_o, 1024, 8192, 0.125f);
    cvt_k<<<cvt_grid(131072), blk, 0, stream>>>(dc_sout_w + (size_t)i*1048576, wbuf, 131072);
    gemm_k<0,1,1><<<dim3(32, 8), blk, 0, stream>>>(attn_o,
        wbuf, dc_sout_b + i*1024, yin, xres, M, 1024, 1024);
    ln_k<0><<<4096, blk, 0, stream>>>(xres, dc_ln2_g + i*1024, dc_ln2_b + i*1024, ln_out);
    cvt_k<<<cvt_grid(131072), blk, 0, stream>>>(dc_q_w + (size_t)i*1048576, wbuf, 131072);
    gemm_k<0,0,0><<<dim3(32, 8), blk, 0, stream>>>(ln_out,
        wbuf, dc_q_b + i*1024, nullptr, qbuf, M, 1024, 1024);
    cvt_k<<<cvt_grid(262144), blk, 0, stream>>>(dc_kv_w + (size_t)i*2097152, wbuf, 262144);
    gemm_k<0,0,0><<<dim3(32, 16), blk, 0, stream>>>(membuf,
        wbuf, dc_kv_b + i*2048, nullptr, kvbuf, M, 2048, 1024);
    attn_k<0><<<dim3(8,128), blk, 0, stream>>>(qbuf, 1024, 8192,
        kvbuf, 2048, 16384, kvbuf+1024, 2048, 16384, attn_o, 1024, 8192, 0.125f);
    cvt_k<<<cvt_grid(131072), blk, 0, stream>>>(dc_cout_w + (size_t)i*1048576, wbuf, 131072);
    gemm_k<0,1,1><<<dim3(32, 8), blk, 0, stream>>>(attn_o,
        wbuf, dc_cout_b + i*1024, xres, xres, M, 1024, 1024);
    ln_k<0><<<4096, blk, 0, stream>>>(xres, dc_ln3_g + i*1024, dc_ln3_b + i*1024, ln_out);
    cvt_k<<<cvt_grid(524288), blk, 0, stream>>>(dc_fc1_w + (size_t)i*4194304, wbuf, 524288);
    gemm_k<1,0,0><<<dim3(32, 32), blk, 0, stream>>>(ln_out,
        wbuf, dc_fc1_b + i*4096, nullptr, hbuf, M, 4096, 1024);
    cvt_k<<<cvt_grid(524288), blk, 0, stream>>>(dc_fc2_w + (size_t)i*4194304, wbuf, 524288);
    gemm_k<0,1,1><<<dim3(32, 8), blk, 0, stream>>>(hbuf,
        wbuf, dc_fc2_b + i*1024, xres, xres, M, 1024, 4096);
  }
  ln_k<1><<<4096, blk, 0, stream>>>(xres, dc_nrm_g, dc_nrm_b, d_out);
}